// Round 20
// baseline (883.249 us; speedup 1.0000x reference)
//
#include <hip/hip_runtime.h>
#include <hip/hip_bf16.h>
#include <math.h>

// ---------------- problem constants ----------------
#define TT     1024      // T
#define METAN  6
#define TT1    1030      // T + META
#define BB     2
#define DD     512
#define HH     8
#define HSZ    64
#define LL     6
#define NVOCAB 32000
#define MROWS  2060      // B*T1
#define MPAD   2176      // 34 * 64
#define SCALE  0.044194173824159216f   // 512^-0.5
#define NPART  16        // LN partial sums per row (32 cols each)

typedef float  f32x4  __attribute__((ext_vector_type(4)));
typedef __bf16 bf16x8 __attribute__((ext_vector_type(8)));

__device__ __forceinline__ __bf16 f2bf(float f) { return (__bf16)f; }  // native RNE cvt

__device__ __forceinline__ void glds16(const __bf16* g, const __bf16* l) {
  __builtin_amdgcn_global_load_lds(
      (const __attribute__((address_space(1))) unsigned int*)g,
      (__attribute__((address_space(3))) unsigned int*)l, 16, 0, 0);
}

// normalize 8 fp32 (register form) -> bf16x8
__device__ __forceinline__ bf16x8 ln8v(float4 v0, float4 v1, float mu, float rs,
                                       float4 g0, float4 g1, float4 b0, float4 b1) {
  float vv[8] = {v0.x, v0.y, v0.z, v0.w, v1.x, v1.y, v1.z, v1.w};
  float gg[8] = {g0.x, g0.y, g0.z, g0.w, g1.x, g1.y, g1.z, g1.w};
  float bb[8] = {b0.x, b0.y, b0.z, b0.w, b1.x, b1.y, b1.z, b1.w};
  bf16x8 r;
#pragma unroll
  for (int j = 0; j < 8; j++) r[j] = f2bf((vv[j] - mu) * rs * gg[j] + bb[j]);
  return r;
}
__device__ __forceinline__ bf16x8 ln8(const float* xp, float mu, float rs,
                                      const float* g, const float* b) {
  return ln8v(*(const float4*)xp, *(const float4*)(xp + 4), mu, rs,
              *(const float4*)g, *(const float4*)(g + 4),
              *(const float4*)b, *(const float4*)(b + 4));
}

__device__ __forceinline__ void row_stats(const float* ps, const float* pq, int row,
                                          float& mu, float& rs) {
  float s = 0.f, q = 0.f;
#pragma unroll
  for (int j = 0; j < NPART; j++) { s += ps[(size_t)row * NPART + j]; q += pq[(size_t)row * NPART + j]; }
  mu = s * (1.0f / 512.0f);
  rs = rsqrtf(fmaxf(q * (1.0f / 512.0f) - mu * mu, 0.f) + 1e-5f);
}

// ---------------- final LN -> compact bf16 rows for LM head ----------------
__global__ void k_lnpw(const float* x, const float* ps, const float* pq,
                       const float* g, const float* b, __bf16* xf)
{
  const int sub = threadIdx.x >> 6;
  const int lane = threadIdx.x & 63;
  int row = blockIdx.x * 4 + sub;
  int sr = (row >> 10) * TT1 + (row & 1023);
  float mu, rs;
  row_stats(ps, pq, sr, mu, rs);
  bf16x8 o = ln8(&x[(size_t)sr * DD + lane * 8], mu, rs, &g[lane * 8], &b[lane * 8]);
  *(bf16x8*)&xf[(size_t)row * DD + lane * 8] = o;
}

// ---------------- merged: 7 weight conversions (64x64 tiles, NT stores) + embedding ----------------
__global__ void k_tcvt8(const float* __restrict__ Wq, const float* __restrict__ Wk,
                        const float* __restrict__ Wv, const float* __restrict__ Wo,
                        const float* __restrict__ W1, const float* __restrict__ W2,
                        const float* __restrict__ Wlm,
                        __bf16* __restrict__ wqkvb, __bf16* __restrict__ wob,
                        __bf16* __restrict__ w1b, __bf16* __restrict__ w2b,
                        __bf16* __restrict__ wlmb,
                        const int* idx, const int* midx, const float* tok,
                        const float* met, float* x, float* ps, float* pq)
{
  int bid = blockIdx.x;
  if (bid >= 8608) {
    // ---- embedding part: 1030 blocks, 2 rows each ----
    const int sub = threadIdx.x >> 7;
    const int tl  = threadIdx.x & 127;
    const int d0  = tl * 4;
    int row = (bid - 8608) * 2 + sub;
    int b = row / TT1, tk = row - b * TT1;
    float v[4];
    if (tk < TT) {
      const float* e = tok + (size_t)idx[b * TT + tk] * DD;
      float pos = (float)(tk / 6);
#pragma unroll
      for (int j = 0; j < 4; j += 2) {
        int i = (d0 + j) >> 1;
        float dv = expf((float)i * (-2.0f * 9.210340371976184f / 512.0f));
        float ang = pos * dv;
        v[j]     = e[d0 + j]     + sinf(ang);
        v[j + 1] = e[d0 + j + 1] + cosf(ang);
      }
    } else {
      const float* e = met + (size_t)midx[b * METAN + (tk - TT)] * DD;
#pragma unroll
      for (int j = 0; j < 4; j++) v[j] = e[d0 + j];
    }
    *(float4*)&x[(size_t)row * DD + d0] = *(float4*)v;
    float s = v[0] + v[1] + v[2] + v[3];
    float q = v[0]*v[0] + v[1]*v[1] + v[2]*v[2] + v[3]*v[3];
#pragma unroll
    for (int msk = 1; msk < 8; msk <<= 1) { s += __shfl_xor(s, msk); q += __shfl_xor(q, msk); }
    if ((tl & 7) == 0) {
      ps[(size_t)row * NPART + (tl >> 3)] = s;
      pq[(size_t)row * NPART + (tl >> 3)] = q;
    }
    return;
  }
  // ---- weight-conversion part: 64x64 transpose tiles, nontemporal bf16 stores ----
  __shared__ float t[64][65];
  const float* in; __bf16* out;
  int gx, gy, C, R, lo_cnt, local;
  long long in_bs, bs_hi, bs_lo;
  if (bid < 1152) {          // Wq/Wk/Wv -> fused qkv weight, 48 (layer,head) batches each
    int job = bid / 384; local = bid - job * 384;
    in = job == 0 ? Wq : (job == 1 ? Wk : Wv);
    out = wqkvb + (size_t)job * 262144;
    gx = 1; gy = 8; R = 512; C = 64; in_bs = 32768; bs_hi = 786432; bs_lo = 32768; lo_cnt = 8;
  } else if (bid < 1536) {
    local = bid - 1152; in = Wo; out = wob;
    gx = 8; gy = 8; R = 512; C = 512; in_bs = 262144; bs_hi = 262144; bs_lo = 0; lo_cnt = 1;
  } else if (bid < 3072) {
    local = bid - 1536; in = W1; out = w1b;
    gx = 32; gy = 8; R = 512; C = 2048; in_bs = 1048576; bs_hi = 1048576; bs_lo = 0; lo_cnt = 1;
  } else if (bid < 4608) {
    local = bid - 3072; in = W2; out = w2b;
    gx = 8; gy = 32; R = 2048; C = 512; in_bs = 1048576; bs_hi = 1048576; bs_lo = 0; lo_cnt = 1;
  } else {
    local = bid - 4608; in = Wlm; out = wlmb;
    gx = 500; gy = 8; R = 512; C = 32000; in_bs = 0; bs_hi = 0; bs_lo = 0; lo_cnt = 1;
  }
  int bx = local % gx; int tmp = local / gx; int by = tmp % gy; int bz = tmp / gy;
  const float* ib = in + (long long)bz * in_bs;
  __bf16* ob = out + (long long)(bz / lo_cnt) * bs_hi + (long long)(bz % lo_cnt) * bs_lo;
  int tx = threadIdx.x & 63, ty = threadIdx.x >> 6;
  int c = bx * 64 + tx;
  for (int j = ty; j < 64; j += 4)
    t[j][tx] = ib[(size_t)(by * 64 + j) * C + c];
  __syncthreads();
  int r = by * 64 + tx;
  for (int j = ty; j < 64; j += 4)
    __builtin_nontemporal_store(f2bf(t[tx][j]), &ob[(size_t)(bx * 64 + j) * R + r]);
}

// ---------------- GEMM tile body: BK=64*KS, global_load_lds staging, dbuf LDS ----------------
// Tile MT x NT, 4 waves as WM x (4/WM). LDS per 64-deep sub-tile: row r's 8 chunks at
// chunk r*8 + (j ^ (r&7)).  KS = sub-tiles per K-step (1 -> BK=64, 2 -> BK=128; KS=2 is
// AMODE 0 only).  AMODE 0: A bf16 [.][K] via glds.  AMODE 1: LN(Ax fp32) on the fly (MT=64).
// MODE 0: outb = bf16(acc (+bias) (ReLU));
// MODE 1: outf = res+acc+bias (+STAT: WM=4, NT=32, 32-col partials);
// MODE 2: outf = acc + bias via LDS-transposed nontemporal dwordx4 stores (rows all valid; WNS=64).
template <int MODE, bool RELU, bool BIAS, int AMODE, int MT, int NT, int WM, bool STAT, int KS>
__device__ __forceinline__ void gemm_tiles(
    unsigned char* smem,
    const __bf16* A, const float* Ax,
    const float* ps, const float* pq,
    const float* lng, const float* lnb,
    const __bf16* __restrict__ Bt, const float* bias,
    const float* res,
    float* outf, __bf16* outb,
    float* ops, float* opq,
    int M, int N, int K, int ntx, int nty)
{
  constexpr int WN  = 4 / WM;
  constexpr int WMS = MT / WM;
  constexpr int WNS = NT / WN;
  constexpr int MR  = WMS / 16;
  constexpr int NR  = WNS / 16;
  constexpr int RA  = MT / 32;
  constexpr int RB  = (NT + 31) / 32;

  __bf16* const Asm = (__bf16*)smem;                      // [2][KS][MT*64]
  __bf16* const Bsm = (__bf16*)smem + 2 * KS * MT * 64;   // [2][KS][NT*64]

  const int tid = threadIdx.x;
  const int lane = tid & 63, w = tid >> 6;
  const int wm = (WN == 1) ? w : (w >> 1);
  const int wn = (WN == 1) ? 0 : (w & 1);
  const int rm = lane & 15, g4 = lane >> 4;
  const int nt = ntx * nty;

  // XCD-bijective swizzle
  int flat = blockIdx.x;
  { const int q = nt >> 3, rr = nt & 7; const int xcd = flat & 7, ii = flat >> 3;
    flat = (xcd < rr ? xcd * (q + 1) : rr * (q + 1) + (xcd - rr) * q) + ii; }
  const int row0 = (flat % ntx) * MT;
  const int col0 = (flat / ntx) * NT;

  f32x4 acc[MR][NR];
  const f32x4 fz = {0.f, 0.f, 0.f, 0.f};
#pragma unroll
  for (int i = 0; i < MR; i++)
#pragma unroll
    for (int j = 0; j < NR; j++) acc[i][j] = fz;

  // ---- staging source pointers (inverse-swizzled per-lane addresses) ----
  const __bf16* bSrc[RB];
#pragma unroll
  for (int i = 0; i < RB; i++) {
    int c = i * 256 + (NT == 32 ? (tid & 255) : tid);
    int r = c >> 3; int j = (c & 7) ^ (r & 7);
    bSrc[i] = Bt + (size_t)(col0 + r) * K + j * 8;
  }
  const __bf16* aSrc[RA];
  const float *Ax0 = nullptr, *gk = nullptr, *bk = nullptr;
  float mu0 = 0.f, rs0 = 0.f;
  int oA0 = 0, oA1 = 0;
  if (AMODE == 0) {
#pragma unroll
    for (int i = 0; i < RA; i++) {
      int c = i * 256 + tid; int r = c >> 3; int j = (c & 7) ^ (r & 7);
      aSrc[i] = A + (size_t)(row0 + r) * K + j * 8;
    }
  } else {
    int srow = tid >> 2, skc = tid & 3;
    int sa0 = row0 + srow;
    Ax0 = Ax + (size_t)sa0 * DD + skc * 8;
    row_stats(ps, pq, sa0, mu0, rs0);
    gk = lng + skc * 8; bk = lnb + skc * 8;
    oA0 = (srow * 8 + (skc ^ (srow & 7))) * 8;
    oA1 = (srow * 8 + ((skc + 4) ^ (srow & 7))) * 8;
  }

  float4 xa0, xa1, xb0, xb1, ga0, ga1, gb0, gb1, ca0, ca1, cb0, cb1;
  auto loadA1 = [&](int k0) {
    xa0 = *(const float4*)(Ax0 + k0);      xa1 = *(const float4*)(Ax0 + k0 + 4);
    xb0 = *(const float4*)(Ax0 + k0 + 32); xb1 = *(const float4*)(Ax0 + k0 + 36);
    ga0 = *(const float4*)(gk + k0);       ga1 = *(const float4*)(gk + k0 + 4);
    gb0 = *(const float4*)(gk + k0 + 32);  gb1 = *(const float4*)(gk + k0 + 36);
    ca0 = *(const float4*)(bk + k0);       ca1 = *(const float4*)(bk + k0 + 4);
    cb0 = *(const float4*)(bk + k0 + 32);  cb1 = *(const float4*)(bk + k0 + 36);
  };
  auto writeA1 = [&](int buf) {
    __bf16* base = Asm + buf * KS * MT * 64;
    *(bf16x8*)(base + oA0) = ln8v(xa0, xa1, mu0, rs0, ga0, ga1, ca0, ca1);
    *(bf16x8*)(base + oA1) = ln8v(xb0, xb1, mu0, rs0, gb0, gb1, cb0, cb1);
  };
  auto stageB = [&](int buf, int k0) {
#pragma unroll
    for (int h = 0; h < KS; h++) {
      if (NT == 32) {
        glds16(bSrc[0] + k0 + h * 64, Bsm + (buf * KS + h) * NT * 64 + (tid & 255) * 8);
      } else {
#pragma unroll
        for (int i = 0; i < RB; i++)
          glds16(bSrc[i] + k0 + h * 64, Bsm + (buf * KS + h) * NT * 64 + (i * 256 + w * 64) * 8);
      }
    }
  };
  auto stageA0 = [&](int buf, int k0) {
#pragma unroll
    for (int h = 0; h < KS; h++)
#pragma unroll
      for (int i = 0; i < RA; i++)
        glds16(aSrc[i] + k0 + h * 64, Asm + (buf * KS + h) * MT * 64 + (i * 256 + w * 64) * 8);
  };

  // ---- prologue ----
  stageB(0, 0);
  if (AMODE == 0) stageA0(0, 0);
  else { loadA1(0); writeA1(0); }
  __syncthreads();

  int cur = 0;
  const int BK = 64 * KS;
  for (int k0 = 0; k0 < K; k0 += BK) {
    const bool nxt = (k0 + BK < K);
    if (nxt) {
      stageB(cur ^ 1, k0 + BK);
      if (AMODE == 0) stageA0(cur ^ 1, k0 + BK);
      else loadA1(k0 + BK);
    }
#pragma unroll
    for (int h = 0; h < KS; h++) {
      const __bf16* Acur = Asm + (cur * KS + h) * MT * 64;
      const __bf16* Bcur = Bsm + (cur * KS + h) * NT * 64;
      bf16x8 af[MR][2], bf[NR][2];
#pragma unroll
      for (int m = 0; m < MR; m++) {
        int r = wm * WMS + m * 16 + rm;
        int c0 = r * 8 + (g4 ^ (r & 7));
        af[m][0] = *(const bf16x8*)(Acur + c0 * 8);
        af[m][1] = *(const bf16x8*)(Acur + (c0 ^ 4) * 8);
      }
#pragma unroll
      for (int n = 0; n < NR; n++) {
        int r = wn * WNS + n * 16 + rm;
        int c0 = r * 8 + (g4 ^ (r & 7));
        bf[n][0] = *(const bf16x8*)(Bcur + c0 * 8);
        bf[n][1] = *(const bf16x8*)(Bcur + (c0 ^ 4) * 8);
      }
#pragma unroll
      for (int t = 0; t < 2; t++)
#pragma unroll
        for (int m = 0; m < MR; m++)
#pragma unroll
          for (int n = 0; n < NR; n++)
            acc[m][n] = __builtin_amdgcn_mfma_f32_16x16x32_bf16(af[m][t], bf[n][t], acc[m][n], 0, 0, 0);
    }
    if (nxt) {
      if (AMODE == 1) writeA1(cur ^ 1);
      __syncthreads();
    }
    cur ^= 1;
  }

  // ---- epilogue ----
  if (MODE == 2) {
    // transpose through LDS scratch -> nontemporal dwordx4 stores (rows all valid).
    __syncthreads();
    float* T = (float*)smem;
    constexpr int CHM = (MR >= 2) ? 2 : 1;
    constexpr int CH  = CHM * 16;
    constexpr int NCH = MR / CHM;
    constexpr int RPR = WNS / 4;            // float4 per row
    constexpr int NRD = CH * RPR / 64;      // store rounds per chunk
    const int wbase = w * (CH * 68);
#pragma unroll
    for (int c = 0; c < NCH; c++) {
#pragma unroll
      for (int mm = 0; mm < CHM; mm++) {
        int m = c * CHM + mm;
#pragma unroll
        for (int n = 0; n < NR; n++) {
          float bvv = BIAS ? bias[col0 + wn * WNS + n * 16 + rm] : 0.f;
#pragma unroll
          for (int r = 0; r < 4; r++)
            T[wbase + (mm * 16 + g4 * 4 + r) * 68 + n * 16 + rm] = acc[m][n][r] + bvv;
        }
      }
#pragma unroll
      for (int i = 0; i < NRD; i++) {
        int flatd = i * 64 + lane;
        int rloc = flatd / RPR;
        int cc = flatd % RPR;
        f32x4 v = *(f32x4*)&T[wbase + rloc * 68 + cc * 4];
        __builtin_nontemporal_store(v,
            (f32x4*)&outf[(size_t)(row0 + wm * WMS + c * CH + rloc) * N + col0 + wn * WNS + cc * 4]);
      }
    }
  } else {
#pragma unroll
    for (int m = 0; m < MR; m++) {
      int row_b = row0 + wm * WMS + m * 16 + g4 * 4;
      float bv[NR];
#pragma unroll
      for (int n = 0; n < NR; n++) bv[n] = BIAS ? bias[col0 + wn * WNS + n * 16 + rm] : 0.f;
#pragma unroll
      for (int r = 0; r < 4; r++) {
        int row = row_b + r;
        float s = 0.f, qq = 0.f;
#pragma unroll
        for (int n = 0; n < NR; n++) {
          int col = col0 + wn * WNS + n * 16 + rm;
          float v = acc[m][n][r] + bv[n];
          if (MODE == 0) {
            if (RELU) v = fmaxf(v, 0.f);
            if (row < M) outb[(size_t)row * N + col] = f2bf(v);
          } else {
            if (row < M) { v += res[(size_t)row * N + col]; outf[(size_t)row * N + col] = v; }
            s += v; qq += v * v;
          }
        }
        if (MODE == 1 && STAT) {
#pragma unroll
          for (int msk = 1; msk < 16; msk <<= 1) { s += __shfl_xor(s, msk); qq += __shfl_xor(qq, msk); }
          if (rm == 0 && row < M) {
            ops[(size_t)row * NPART + (col0 >> 5)] = s;
            opq[(size_t)row * NPART + (col0 >> 5)] = qq;
          }
        }
      }
    }
  }
}

// KS=1 wrapper (32 KB LDS) -> up to 3 blocks/CU
template <int MODE, bool RELU, bool BIAS, int AMODE, int MT, int NT, int WM, bool STAT>
__global__ __launch_bounds__(256, 3) void k_gemm(
    const __bf16* A, const float* Ax, const float* ps, const float* pq,
    const float* lng, const float* lnb,
    const __bf16* __restrict__ Bt, const float* bias, const float* res,
    float* outf, __bf16* outb, float* ops, float* opq,
    int M, int N, int K, int ntx, int nty)
{
  __shared__ __align__(16) unsigned char smem[(MT + NT) * 256];
  gemm_tiles<MODE, RELU, BIAS, AMODE, MT, NT, WM, STAT, 1>(
      smem, A, Ax, ps, pq, lng, lnb, Bt, bias, res, outf, outb, ops, opq,
      M, N, K, ntx, nty);
}

// BK=128 wrapper (AMODE 0 only): (MT+NT)*512 B LDS; NT=32 -> 48 KB -> 3 blocks/CU
template <int MODE, bool RELU, bool BIAS, int MT, int NT, int WM, bool STAT>
__global__ __launch_bounds__(256, 3) void k_gemm2(
    const __bf16* A, const float* Ax, const float* ps, const float* pq,
    const float* lng, const float* lnb,
    const __bf16* __restrict__ Bt, const float* bias, const float* res,
    float* outf, __bf16* outb, float* ops, float* opq,
    int M, int N, int K, int ntx, int nty)
{
  __shared__ __align__(16) unsigned char smem[(MT + NT) * 512];
  gemm_tiles<MODE, RELU, BIAS, 0, MT, NT, WM, STAT, 2>(
      smem, A, Ax, ps, pq, lng, lnb, Bt, bias, res, outf, outb, ops, opq,
      M, N, K, ntx, nty);
}

// LM-head wrapper: 128x128 tile, BK=64, 64 KB LDS -> 2 blocks/CU
template <int MODE, bool RELU, bool BIAS, int AMODE, int MT, int NT, int WM, bool STAT>
__global__ __launch_bounds__(256, 2) void k_gemmL(
    const __bf16* A, const float* Ax, const float* ps, const float* pq,
    const float* lng, const float* lnb,
    const __bf16* __restrict__ Bt, const float* bias, const float* res,
    float* outf, __bf16* outb, float* ops, float* opq,
    int M, int N, int K, int ntx, int nty)
{
  __shared__ __align__(16) unsigned char smem[(MT + NT) * 256];
  gemm_tiles<MODE, RELU, BIAS, AMODE, MT, NT, WM, STAT, 1>(
      smem, A, Ax, ps, pq, lng, lnb, Bt, bias, res, outf, outb, ops, opq,
      M, N, K, ntx, nty);
}

// ---------------- fused masked attention: dbuf K/V LDS, reg prefetch, 1 barrier/tile ----------------
// Work-balanced block order: blockIdx 0..255 carry the longest q-tiles (one per CU),
// trailing 16 blocks are the 1-tile q_level=0 blocks that double up on CUs.
__global__ __launch_bounds__(256) void k_attnw(const __bf16* qkv, __bf16* ob)
{
  __shared__ __align__(16) __bf16 Ks[2][64][72];     // [buf][key row][hs]
  __shared__ __align__(16) __bf16 Vs[2][64][72];     // [buf][hs][key]
  __shared__ __align__(16) __bf16 Ps[4][16][72];     // per wave: q row x key (wave-private)

  const int tid = threadIdx.x;
  const int lane = tid & 63, w = tid >> 6;
  const int rm = lane & 15, g4 = lane >> 4;
  const int skey = tid >> 3;            // 0..31
  const int shs = (tid & 7) * 8;
  const size_t rsd = 1536;
  const f32x4 fz = {0.f, 0.f, 0.f, 0.f};

  // descending-work relabel: q_level 16..0 as blockIdx rises
  const int q_level = 16 - (blockIdx.x >> 4);
  const int bh = blockIdx.x & 15;
  const int b = bh >> 3, h = bh & 7;
  const int q0 = q_level * 64;
  const int qw = q0 + w * 16;

  const __bf16* qb = qkv + (size_t)b * TT1 * rsd + h * HSZ;
  const __bf16* kb = qb + 512;
  const __bf16* vb = qb + 1024;

  bf16x8 aq[2];
  {
    const __bf16* qp = qb + (size_t)(qw + rm) * rsd + 8 * g4;
    aq[0] = *(const bf16x8*)qp;
    aq[1] = *(const bf16x8*)(qp + 32);
  }

  int ae_[4];
#pragma unroll
  for (int r = 0; r < 4; r++) {
    int qr = qw + g4 * 4 + r;
    ae_[r] = (qr / 6 + 1) * 6;          // chunked-causal limit
  }

  float m_[4], l_[4];
  f32x4 accO[4];
#pragma unroll
  for (int j = 0; j < 4; j++) accO[j] = fz;
#pragma unroll
  for (int r = 0; r < 4; r++) { m_[r] = -1e30f; l_[r] = 0.f; }

  int aemax = ((q0 + 63) / 6 + 1) * 6;
  if (aemax > TT) aemax = TT;
  const int ntile = (aemax + 63) >> 6;  // 64-key main tiles cover [0, ntile*64) <= 1024

  // K/V register staging + buffered write helpers
  bf16x8 rk0, rk1, rv0, rv1;
  auto kvload = [&](int kt) {
    rk0 = *(const bf16x8*)(kb + (size_t)(kt + skey) * rsd + shs);
    rk1 = *(const bf16x8*)(kb + (size_t)(kt + skey + 32) * rsd + shs);
    rv0 = *(const bf16x8*)(vb + (size_t)(kt + skey) * rsd + shs);
    rv1 = *(const bf16x8*)(vb + (size_t)(kt + skey + 32) * rsd + shs);
  };
  auto kvwrite = [&](int buf) {
    *(bf16x8*)&Ks[buf][skey][shs]      = rk0;
    *(bf16x8*)&Ks[buf][skey + 32][shs] = rk1;
#pragma unroll
    for (int j = 0; j < 8; j++) {
      Vs[buf][shs + j][skey]      = rv0[j];
      Vs[buf][shs + j][skey + 32] = rv1[j];
    }
  };
  auto ktile = [&](int tt) { return (tt == ntile) ? TT : tt * 64; };

  // ---- prologue: tile 0 into buf 0 ----
  kvload(ktile(0));
  kvwrite(0);
  __syncthreads();

  int cur = 0;
  for (int tt = 0; tt <= ntile; ++tt) {
    const bool meta = (tt == ntile);
    const int kt = ktile(tt);
    const bool nxt = (tt < ntile);
    if (nxt) kvload(ktile(tt + 1));     // HBM latency hides under this tile's compute

    // S = Q K^T  (16 q x 64 keys per wave)
    f32x4 s[4];
    __builtin_amdgcn_s_setprio(1);
#pragma unroll
    for (int nt2 = 0; nt2 < 4; nt2++) {
      f32x4 a = fz;
      bf16x8 bk0 = *(const bf16x8*)&Ks[cur][nt2 * 16 + rm][8 * g4];
      bf16x8 bk1 = *(const bf16x8*)&Ks[cur][nt2 * 16 + rm][32 + 8 * g4];
      a = __builtin_amdgcn_mfma_f32_16x16x32_bf16(aq[0], bk0, a, 0, 0, 0);
      a = __builtin_amdgcn_mfma_f32_16x16x32_bf16(aq[1], bk1, a, 0, 0, 0);
      s[nt2] = a;
    }
    __builtin_amdgcn_s_setprio(0);

    float alpha[4];
#pragma unroll
    for (int r = 0; r < 4; r++) {
      int lim = meta ? TT1 : ae_[r];
      float sv[4];
#pragma unroll
      for (int i = 0; i < 4; i++) {
        sv[i] = s[i][r] * SCALE;
        if (kt + i * 16 + rm >= lim) sv[i] = -1e30f;
      }
      float tm = fmaxf(fmaxf(sv[0], sv[1]), fmaxf(sv[2], sv[3]));
#pragma unroll
      for (int msk = 1; msk < 16; msk <<= 1) tm = fmaxf(tm, __shfl_xor(tm, msk));
      float mn = fmaxf(m_[r], tm);
      float pp[4]; float ts = 0.f;
#pragma unroll
      for (int i = 0; i < 4; i++) { pp[i] = __expf(sv[i] - mn); ts += pp[i]; }
#pragma unroll
      for (int msk = 1; msk < 16; msk <<= 1) ts += __shfl_xor(ts, msk);
      alpha[r] = __expf(m_[r] - mn);
      l_[r] = l_[r] * alpha[r] + ts;
      m_[r] = mn;
#pragma unroll
      for (int i = 0; i < 4; i++) Ps[w][g4 * 4 + r][rm + i * 16] = f2bf(pp[i]);
    }
#pragma unroll
    for (int j = 0; j < 4; j++)
#pragma unroll
      for (int r = 0; r < 4; r++) accO[j][r] *= alpha[r];
    // Ps[w] is wave-private: intra-wave ds_write -> ds_read ordering is HW/compiler enforced

    bf16x8 pa0 = *(const bf16x8*)&Ps[w][rm][8 * g4];
    bf16x8 pa1 = *(const bf16x8*)&Ps[w][rm][32 + 8 * g4];
    __builtin_amdgcn_s_setprio(1);
#pragma unroll
    for (int j = 0; j < 4; j++) {
      bf16x8 bv0 = *(const bf16x8*)&Vs[cur][j * 16 + rm][8 * g4];
      bf16x8 bv1 = *(const bf16x8*)&Vs[cur][j * 16 + rm][32 + 8 * g4];
      accO[j] = __builtin_amdgcn_mfma_f32_16x16x32_bf16(pa0, bv0, accO[j], 0, 0, 0);
      accO[j] = __builtin_amdgcn_mfma_f32_16x16x32_bf16(pa1, bv1, accO[j], 0, 0, 0);
    }
    __builtin_amdgcn_s_setprio(0);

    if (nxt) {
      kvwrite(cur ^ 1);                 // other waves may still read buf[cur] - disjoint
      __syncthreads();                  // buf[cur^1] ready; prior reads of it long done
    }
    cur ^= 1;
  }

#pragma unroll
  for (int r = 0; r < 4; r++) {
    int q = qw + g4 * 4 + r;
    if (q < TT1) {
      float rl = 1.0f / l_[r];
#pragma unroll
      for (int j = 0; j < 4; j++)
        ob[((size_t)b * TT1 + q) * DD + h * HSZ + j * 16 + rm] = f2bf(accO[j][r] * rl);
    }
  }
}

// ---------------- host launcher ----------------
extern "C" void kernel_launch(void* const* d_in, const int* in_sizes, int n_in,
                              void* d_out, int out_size, void* d_ws, size_t ws_size,
                              hipStream_t stream)
{
  const int*   idx   = (const int*)d_in[0];
  const int*   midx  = (const int*)d_in[1];
  const float* tok   = (const float*)d_in[2];
  const float* metae = (const float*)d_in[3];
  const float* Wq    = (const float*)d_in[4];
  const float* Wk    = (const float*)d_in[5];
  const float* Wv    = (const float*)d_in[6];
  const float* Wo    = (const float*)d_in[7];
  const float* bo    = (const float*)d_in[8];
  const float* W1    = (const float*)d_in[9];
  const float* b1    = (const float*)d_in[10];
  const float* W2    = (const float*)d_in[11];
  const float* b2    = (const float*)d_in[12];
  const float* ln1g  = (const float*)d_in[13];
  const float* ln1b  = (const float*)d_in[14];
  const float* ln2g  = (const float*)d_in[15];
  const float* ln2b  = (const float*)d_in[16];
  const float* lnfg  = (const float*)d_in[17];
  const float* lnfb  = (const float*)d_in[18];
  const float* Wlm   = (const float*)d_in[19];
  const float* blm   = (const float*)d_in[20];
  float* out = (float*)d_out;

  char* p = (char*)d_ws;
  auto alloc = [&](size_t bytes) { void* r = (void*)p; p += (bytes + 255) & ~(size_t)255; return r; };
  float*  x     = (float*)alloc((size_t)MPAD * 512 * 4);
  float*  ps_   = (float*)alloc((size_t)MPAD * NPART * 4);
  float*  pq_   = (float*)alloc((size_t)MPAD * NPART * 4);
  __bf16* qkv   = (__bf16*)alloc((size_t)MPAD * 1536 * 2);
  __bf16* obuf  = (__bf16*)alloc((size_t)MPAD * 512 * 2);
  __bf16* f1    = (__bf16*)alloc((size_t)MPAD * 2048 * 2);
  __bf16* xf    = (__bf16*)alloc((size_t)2048 * 512 * 2);
  __bf16* wqkvb = (__bf16*)alloc((size_t)6 * 1536 * 512 * 2);
  __bf16* wob   = (__bf16*)alloc((size_t)6 * 512 * 512 * 2);
  __bf16* w1b   = (__bf16*)alloc((size_t)6 * 2048 * 512 * 2);
  __bf16* w2b   = (__bf16*)alloc((size_t)6 * 512 * 2048 * 2);
  __bf16* wlmb  = (__bf16*)alloc((size_t)NVOCAB * 512 * 2);
  (void)in_sizes; (void)n_in; (void)out_size; (void)ws_size;

  // 1) weight conversions (64x64 tiles, NT stores) + embedding, one dispatch (8608 + 1030)
  k_tcvt8<<<dim3(9638), 256, 0, stream>>>(Wq, Wk, Wv, Wo, W1, W2, Wlm,
                                          wqkvb, wob, w1b, w2b, wlmb,
                                          idx, midx, tok, metae, x, ps_, pq_);

  for (int l = 0; l < LL; ++l) {
    // QKV projection with fused ln1 (64x64 tiles, BK=64, 816 blocks)
    k_gemm<0, false, false, 1, 64, 64, 4, false><<<dim3(816), 256, 0, stream>>>(
        nullptr, x, ps_, pq_, ln1g + l * 512, ln1b + l * 512,
        wqkvb + (size_t)l * 786432, nullptr, nullptr, nullptr, qkv,
        nullptr, nullptr, MROWS, 1536, 512, 34, 24);
    // attention (272 blocks, dbuf K/V, 1 barrier/tile, balanced order)
    k_attnw<<<dim3(272), 256, 0, stream>>>(qkv, obuf);
    // Wo projection + residual + LN partials (64x32 tiles, BK=128, 544 blocks)
    k_gemm2<1, false, true, 64, 32, 4, true><<<dim3(544), 256, 0, stream>>>(
        obuf, nullptr, nullptr, nullptr, nullptr, nullptr,
        wob + (size_t)l * 262144, bo + l * 512, x, x, nullptr,
        ps_, pq_, MROWS, 512, 512, 34, 16);
    // FFN1 with fused ln2 (64x64 tiles, BK=64, 1088 blocks)
    k_gemm<0, true, true, 1, 64, 64, 4, false><<<dim3(1088), 256, 0, stream>>>(
        nullptr, x, ps_, pq_, ln2g + l * 512, ln2b + l * 512,
        w1b + (size_t)l * 1048576, b1 + l * 2048, nullptr, nullptr, f1,
        nullptr, nullptr, MROWS, 2048, 512, 34, 32);
    // FFN2 + residual + LN partials (64x32 tiles, BK=128, 544 blocks)
    k_gemm2<1, false, true, 64, 32, 4, true><<<dim3(544), 256, 0, stream>>>(
        f1, nullptr, nullptr, nullptr, nullptr, nullptr,
        w2b + (size_t)l * 1048576, b2 + l * 512, x, x, nullptr,
        ps_, pq_, MROWS, 512, 2048, 34, 16);
  }

  // final LN -> compact bf16 rows, then LM head (128x128 tiles, 16x250 = 4000 blocks)
  k_lnpw<<<dim3(512), 256, 0, stream>>>(x, ps_, pq_, lnfg, lnfb, xf);
  k_gemmL<2, false, true, 0, 128, 128, 2, false><<<dim3(4000), 256, 0, stream>>>(
      xf, nullptr, nullptr, nullptr, nullptr, nullptr,
      wlmb, blm, nullptr, out, nullptr, nullptr, nullptr, 2048, NVOCAB, 512, 16, 250);
}

// Round 21
// 786.396 us; speedup vs baseline: 1.1232x; 1.1232x over previous
//
#include <hip/hip_runtime.h>
#include <hip/hip_bf16.h>
#include <math.h>

// ---------------- problem constants ----------------
#define TT     1024      // T
#define METAN  6
#define TT1    1030      // T + META
#define BB     2
#define DD     512
#define HH     8
#define HSZ    64
#define LL     6
#define NVOCAB 32000
#define MROWS  2060      // B*T1
#define MPAD   2176      // 34 * 64
#define SCALE  0.044194173824159216f   // 512^-0.5
#define NPART  16        // LN partial sums per row (32 cols each)

typedef float  f32x4  __attribute__((ext_vector_type(4)));
typedef __bf16 bf16x8 __attribute__((ext_vector_type(8)));

__device__ __forceinline__ __bf16 f2bf(float f) { return (__bf16)f; }  // native RNE cvt

__device__ __forceinline__ void glds16(const __bf16* g, const __bf16* l) {
  __builtin_amdgcn_global_load_lds(
      (const __attribute__((address_space(1))) unsigned int*)g,
      (__attribute__((address_space(3))) unsigned int*)l, 16, 0, 0);
}

// normalize 8 fp32 (register form) -> bf16x8
__device__ __forceinline__ bf16x8 ln8v(float4 v0, float4 v1, float mu, float rs,
                                       float4 g0, float4 g1, float4 b0, float4 b1) {
  float vv[8] = {v0.x, v0.y, v0.z, v0.w, v1.x, v1.y, v1.z, v1.w};
  float gg[8] = {g0.x, g0.y, g0.z, g0.w, g1.x, g1.y, g1.z, g1.w};
  float bb[8] = {b0.x, b0.y, b0.z, b0.w, b1.x, b1.y, b1.z, b1.w};
  bf16x8 r;
#pragma unroll
  for (int j = 0; j < 8; j++) r[j] = f2bf((vv[j] - mu) * rs * gg[j] + bb[j]);
  return r;
}
__device__ __forceinline__ bf16x8 ln8(const float* xp, float mu, float rs,
                                      const float* g, const float* b) {
  return ln8v(*(const float4*)xp, *(const float4*)(xp + 4), mu, rs,
              *(const float4*)g, *(const float4*)(g + 4),
              *(const float4*)b, *(const float4*)(b + 4));
}

__device__ __forceinline__ void row_stats(const float* ps, const float* pq, int row,
                                          float& mu, float& rs) {
  float s = 0.f, q = 0.f;
#pragma unroll
  for (int j = 0; j < NPART; j++) { s += ps[(size_t)row * NPART + j]; q += pq[(size_t)row * NPART + j]; }
  mu = s * (1.0f / 512.0f);
  rs = rsqrtf(fmaxf(q * (1.0f / 512.0f) - mu * mu, 0.f) + 1e-5f);
}

// ---------------- final LN -> compact bf16 rows for LM head ----------------
__global__ void k_lnpw(const float* x, const float* ps, const float* pq,
                       const float* g, const float* b, __bf16* xf)
{
  const int sub = threadIdx.x >> 6;
  const int lane = threadIdx.x & 63;
  int row = blockIdx.x * 4 + sub;
  int sr = (row >> 10) * TT1 + (row & 1023);
  float mu, rs;
  row_stats(ps, pq, sr, mu, rs);
  bf16x8 o = ln8(&x[(size_t)sr * DD + lane * 8], mu, rs, &g[lane * 8], &b[lane * 8]);
  *(bf16x8*)&xf[(size_t)row * DD + lane * 8] = o;
}

// ---------------- merged: 7 weight conversions (64x64 tiles) + embedding ----------------
__global__ void k_tcvt8(const float* __restrict__ Wq, const float* __restrict__ Wk,
                        const float* __restrict__ Wv, const float* __restrict__ Wo,
                        const float* __restrict__ W1, const float* __restrict__ W2,
                        const float* __restrict__ Wlm,
                        __bf16* __restrict__ wqkvb, __bf16* __restrict__ wob,
                        __bf16* __restrict__ w1b, __bf16* __restrict__ w2b,
                        __bf16* __restrict__ wlmb,
                        const int* idx, const int* midx, const float* tok,
                        const float* met, float* x, float* ps, float* pq)
{
  int bid = blockIdx.x;
  if (bid >= 8608) {
    // ---- embedding part: 1030 blocks, 2 rows each ----
    const int sub = threadIdx.x >> 7;
    const int tl  = threadIdx.x & 127;
    const int d0  = tl * 4;
    int row = (bid - 8608) * 2 + sub;
    int b = row / TT1, tk = row - b * TT1;
    float v[4];
    if (tk < TT) {
      const float* e = tok + (size_t)idx[b * TT + tk] * DD;
      float pos = (float)(tk / 6);
#pragma unroll
      for (int j = 0; j < 4; j += 2) {
        int i = (d0 + j) >> 1;
        float dv = expf((float)i * (-2.0f * 9.210340371976184f / 512.0f));
        float ang = pos * dv;
        v[j]     = e[d0 + j]     + sinf(ang);
        v[j + 1] = e[d0 + j + 1] + cosf(ang);
      }
    } else {
      const float* e = met + (size_t)midx[b * METAN + (tk - TT)] * DD;
#pragma unroll
      for (int j = 0; j < 4; j++) v[j] = e[d0 + j];
    }
    *(float4*)&x[(size_t)row * DD + d0] = *(float4*)v;
    float s = v[0] + v[1] + v[2] + v[3];
    float q = v[0]*v[0] + v[1]*v[1] + v[2]*v[2] + v[3]*v[3];
#pragma unroll
    for (int msk = 1; msk < 8; msk <<= 1) { s += __shfl_xor(s, msk); q += __shfl_xor(q, msk); }
    if ((tl & 7) == 0) {
      ps[(size_t)row * NPART + (tl >> 3)] = s;
      pq[(size_t)row * NPART + (tl >> 3)] = q;
    }
    return;
  }
  // ---- weight-conversion part: 64x64 transpose tiles, regular cached stores ----
  __shared__ float t[64][65];
  const float* in; __bf16* out;
  int gx, gy, C, R, lo_cnt, local;
  long long in_bs, bs_hi, bs_lo;
  if (bid < 1152) {          // Wq/Wk/Wv -> fused qkv weight, 48 (layer,head) batches each
    int job = bid / 384; local = bid - job * 384;
    in = job == 0 ? Wq : (job == 1 ? Wk : Wv);
    out = wqkvb + (size_t)job * 262144;
    gx = 1; gy = 8; R = 512; C = 64; in_bs = 32768; bs_hi = 786432; bs_lo = 32768; lo_cnt = 8;
  } else if (bid < 1536) {
    local = bid - 1152; in = Wo; out = wob;
    gx = 8; gy = 8; R = 512; C = 512; in_bs = 262144; bs_hi = 262144; bs_lo = 0; lo_cnt = 1;
  } else if (bid < 3072) {
    local = bid - 1536; in = W1; out = w1b;
    gx = 32; gy = 8; R = 512; C = 2048; in_bs = 1048576; bs_hi = 1048576; bs_lo = 0; lo_cnt = 1;
  } else if (bid < 4608) {
    local = bid - 3072; in = W2; out = w2b;
    gx = 8; gy = 32; R = 2048; C = 512; in_bs = 1048576; bs_hi = 1048576; bs_lo = 0; lo_cnt = 1;
  } else {
    local = bid - 4608; in = Wlm; out = wlmb;
    gx = 500; gy = 8; R = 512; C = 32000; in_bs = 0; bs_hi = 0; bs_lo = 0; lo_cnt = 1;
  }
  int bx = local % gx; int tmp = local / gx; int by = tmp % gy; int bz = tmp / gy;
  const float* ib = in + (long long)bz * in_bs;
  __bf16* ob = out + (long long)(bz / lo_cnt) * bs_hi + (long long)(bz % lo_cnt) * bs_lo;
  int tx = threadIdx.x & 63, ty = threadIdx.x >> 6;
  int c = bx * 64 + tx;
  for (int j = ty; j < 64; j += 4)
    t[j][tx] = ib[(size_t)(by * 64 + j) * C + c];
  __syncthreads();
  int r = by * 64 + tx;
  for (int j = ty; j < 64; j += 4)
    ob[(size_t)(bx * 64 + j) * R + r] = f2bf(t[tx][j]);
}

// ---------------- GEMM tile body: BK=64*KS, global_load_lds staging, dbuf LDS ----------------
// Tile MT x NT, 4 waves as WM x (4/WM). LDS per 64-deep sub-tile: row r's 8 chunks at
// chunk r*8 + (j ^ (r&7)).  KS = sub-tiles per K-step (1 -> BK=64, 2 -> BK=128; KS=2 is
// AMODE 0 only).  AMODE 0: A bf16 [.][K] via glds.  AMODE 1: LN(Ax fp32) on the fly (MT=64).
// MODE 0: outb = bf16(acc (+bias) (ReLU));
// MODE 1: outf = res+acc+bias (+STAT: WM=4, NT=32, 32-col partials);
// MODE 2: outf = acc + bias via LDS-transposed nontemporal dwordx4 stores (rows all valid; WNS=64).
template <int MODE, bool RELU, bool BIAS, int AMODE, int MT, int NT, int WM, bool STAT, int KS>
__device__ __forceinline__ void gemm_tiles(
    unsigned char* smem,
    const __bf16* A, const float* Ax,
    const float* ps, const float* pq,
    const float* lng, const float* lnb,
    const __bf16* __restrict__ Bt, const float* bias,
    const float* res,
    float* outf, __bf16* outb,
    float* ops, float* opq,
    int M, int N, int K, int ntx, int nty)
{
  constexpr int WN  = 4 / WM;
  constexpr int WMS = MT / WM;
  constexpr int WNS = NT / WN;
  constexpr int MR  = WMS / 16;
  constexpr int NR  = WNS / 16;
  constexpr int RA  = MT / 32;
  constexpr int RB  = (NT + 31) / 32;

  __bf16* const Asm = (__bf16*)smem;                      // [2][KS][MT*64]
  __bf16* const Bsm = (__bf16*)smem + 2 * KS * MT * 64;   // [2][KS][NT*64]

  const int tid = threadIdx.x;
  const int lane = tid & 63, w = tid >> 6;
  const int wm = (WN == 1) ? w : (w >> 1);
  const int wn = (WN == 1) ? 0 : (w & 1);
  const int rm = lane & 15, g4 = lane >> 4;
  const int nt = ntx * nty;

  // XCD-bijective swizzle
  int flat = blockIdx.x;
  { const int q = nt >> 3, rr = nt & 7; const int xcd = flat & 7, ii = flat >> 3;
    flat = (xcd < rr ? xcd * (q + 1) : rr * (q + 1) + (xcd - rr) * q) + ii; }
  const int row0 = (flat % ntx) * MT;
  const int col0 = (flat / ntx) * NT;

  f32x4 acc[MR][NR];
  const f32x4 fz = {0.f, 0.f, 0.f, 0.f};
#pragma unroll
  for (int i = 0; i < MR; i++)
#pragma unroll
    for (int j = 0; j < NR; j++) acc[i][j] = fz;

  // ---- staging source pointers (inverse-swizzled per-lane addresses) ----
  const __bf16* bSrc[RB];
#pragma unroll
  for (int i = 0; i < RB; i++) {
    int c = i * 256 + (NT == 32 ? (tid & 255) : tid);
    int r = c >> 3; int j = (c & 7) ^ (r & 7);
    bSrc[i] = Bt + (size_t)(col0 + r) * K + j * 8;
  }
  const __bf16* aSrc[RA];
  const float *Ax0 = nullptr, *gk = nullptr, *bk = nullptr;
  float mu0 = 0.f, rs0 = 0.f;
  int oA0 = 0, oA1 = 0;
  if (AMODE == 0) {
#pragma unroll
    for (int i = 0; i < RA; i++) {
      int c = i * 256 + tid; int r = c >> 3; int j = (c & 7) ^ (r & 7);
      aSrc[i] = A + (size_t)(row0 + r) * K + j * 8;
    }
  } else {
    int srow = tid >> 2, skc = tid & 3;
    int sa0 = row0 + srow;
    Ax0 = Ax + (size_t)sa0 * DD + skc * 8;
    row_stats(ps, pq, sa0, mu0, rs0);
    gk = lng + skc * 8; bk = lnb + skc * 8;
    oA0 = (srow * 8 + (skc ^ (srow & 7))) * 8;
    oA1 = (srow * 8 + ((skc + 4) ^ (srow & 7))) * 8;
  }

  float4 xa0, xa1, xb0, xb1, ga0, ga1, gb0, gb1, ca0, ca1, cb0, cb1;
  auto loadA1 = [&](int k0) {
    xa0 = *(const float4*)(Ax0 + k0);      xa1 = *(const float4*)(Ax0 + k0 + 4);
    xb0 = *(const float4*)(Ax0 + k0 + 32); xb1 = *(const float4*)(Ax0 + k0 + 36);
    ga0 = *(const float4*)(gk + k0);       ga1 = *(const float4*)(gk + k0 + 4);
    gb0 = *(const float4*)(gk + k0 + 32);  gb1 = *(const float4*)(gk + k0 + 36);
    ca0 = *(const float4*)(bk + k0);       ca1 = *(const float4*)(bk + k0 + 4);
    cb0 = *(const float4*)(bk + k0 + 32);  cb1 = *(const float4*)(bk + k0 + 36);
  };
  auto writeA1 = [&](int buf) {
    __bf16* base = Asm + buf * KS * MT * 64;
    *(bf16x8*)(base + oA0) = ln8v(xa0, xa1, mu0, rs0, ga0, ga1, ca0, ca1);
    *(bf16x8*)(base + oA1) = ln8v(xb0, xb1, mu0, rs0, gb0, gb1, cb0, cb1);
  };
  auto stageB = [&](int buf, int k0) {
#pragma unroll
    for (int h = 0; h < KS; h++) {
      if (NT == 32) {
        glds16(bSrc[0] + k0 + h * 64, Bsm + (buf * KS + h) * NT * 64 + (tid & 255) * 8);
      } else {
#pragma unroll
        for (int i = 0; i < RB; i++)
          glds16(bSrc[i] + k0 + h * 64, Bsm + (buf * KS + h) * NT * 64 + (i * 256 + w * 64) * 8);
      }
    }
  };
  auto stageA0 = [&](int buf, int k0) {
#pragma unroll
    for (int h = 0; h < KS; h++)
#pragma unroll
      for (int i = 0; i < RA; i++)
        glds16(aSrc[i] + k0 + h * 64, Asm + (buf * KS + h) * MT * 64 + (i * 256 + w * 64) * 8);
  };

  // ---- prologue ----
  stageB(0, 0);
  if (AMODE == 0) stageA0(0, 0);
  else { loadA1(0); writeA1(0); }
  __syncthreads();

  int cur = 0;
  const int BK = 64 * KS;
  for (int k0 = 0; k0 < K; k0 += BK) {
    const bool nxt = (k0 + BK < K);
    if (nxt) {
      stageB(cur ^ 1, k0 + BK);
      if (AMODE == 0) stageA0(cur ^ 1, k0 + BK);
      else loadA1(k0 + BK);
    }
#pragma unroll
    for (int h = 0; h < KS; h++) {
      const __bf16* Acur = Asm + (cur * KS + h) * MT * 64;
      const __bf16* Bcur = Bsm + (cur * KS + h) * NT * 64;
      bf16x8 af[MR][2], bf[NR][2];
#pragma unroll
      for (int m = 0; m < MR; m++) {
        int r = wm * WMS + m * 16 + rm;
        int c0 = r * 8 + (g4 ^ (r & 7));
        af[m][0] = *(const bf16x8*)(Acur + c0 * 8);
        af[m][1] = *(const bf16x8*)(Acur + (c0 ^ 4) * 8);
      }
#pragma unroll
      for (int n = 0; n < NR; n++) {
        int r = wn * WNS + n * 16 + rm;
        int c0 = r * 8 + (g4 ^ (r & 7));
        bf[n][0] = *(const bf16x8*)(Bcur + c0 * 8);
        bf[n][1] = *(const bf16x8*)(Bcur + (c0 ^ 4) * 8);
      }
#pragma unroll
      for (int t = 0; t < 2; t++)
#pragma unroll
        for (int m = 0; m < MR; m++)
#pragma unroll
          for (int n = 0; n < NR; n++)
            acc[m][n] = __builtin_amdgcn_mfma_f32_16x16x32_bf16(af[m][t], bf[n][t], acc[m][n], 0, 0, 0);
    }
    if (nxt) {
      if (AMODE == 1) writeA1(cur ^ 1);
      __syncthreads();
    }
    cur ^= 1;
  }

  // ---- epilogue ----
  if (MODE == 2) {
    // transpose through LDS scratch -> nontemporal dwordx4 stores (rows all valid).
    __syncthreads();
    float* T = (float*)smem;
    constexpr int CHM = (MR >= 2) ? 2 : 1;
    constexpr int CH  = CHM * 16;
    constexpr int NCH = MR / CHM;
    constexpr int RPR = WNS / 4;            // float4 per row
    constexpr int NRD = CH * RPR / 64;      // store rounds per chunk
    const int wbase = w * (CH * 68);
#pragma unroll
    for (int c = 0; c < NCH; c++) {
#pragma unroll
      for (int mm = 0; mm < CHM; mm++) {
        int m = c * CHM + mm;
#pragma unroll
        for (int n = 0; n < NR; n++) {
          float bvv = BIAS ? bias[col0 + wn * WNS + n * 16 + rm] : 0.f;
#pragma unroll
          for (int r = 0; r < 4; r++)
            T[wbase + (mm * 16 + g4 * 4 + r) * 68 + n * 16 + rm] = acc[m][n][r] + bvv;
        }
      }
#pragma unroll
      for (int i = 0; i < NRD; i++) {
        int flatd = i * 64 + lane;
        int rloc = flatd / RPR;
        int cc = flatd % RPR;
        f32x4 v = *(f32x4*)&T[wbase + rloc * 68 + cc * 4];
        __builtin_nontemporal_store(v,
            (f32x4*)&outf[(size_t)(row0 + wm * WMS + c * CH + rloc) * N + col0 + wn * WNS + cc * 4]);
      }
    }
  } else {
#pragma unroll
    for (int m = 0; m < MR; m++) {
      int row_b = row0 + wm * WMS + m * 16 + g4 * 4;
      float bv[NR];
#pragma unroll
      for (int n = 0; n < NR; n++) bv[n] = BIAS ? bias[col0 + wn * WNS + n * 16 + rm] : 0.f;
#pragma unroll
      for (int r = 0; r < 4; r++) {
        int row = row_b + r;
        float s = 0.f, qq = 0.f;
#pragma unroll
        for (int n = 0; n < NR; n++) {
          int col = col0 + wn * WNS + n * 16 + rm;
          float v = acc[m][n][r] + bv[n];
          if (MODE == 0) {
            if (RELU) v = fmaxf(v, 0.f);
            if (row < M) outb[(size_t)row * N + col] = f2bf(v);
          } else {
            if (row < M) { v += res[(size_t)row * N + col]; outf[(size_t)row * N + col] = v; }
            s += v; qq += v * v;
          }
        }
        if (MODE == 1 && STAT) {
#pragma unroll
          for (int msk = 1; msk < 16; msk <<= 1) { s += __shfl_xor(s, msk); qq += __shfl_xor(qq, msk); }
          if (rm == 0 && row < M) {
            ops[(size_t)row * NPART + (col0 >> 5)] = s;
            opq[(size_t)row * NPART + (col0 >> 5)] = qq;
          }
        }
      }
    }
  }
}

// KS=1 wrapper (32 KB LDS) -> up to 3 blocks/CU
template <int MODE, bool RELU, bool BIAS, int AMODE, int MT, int NT, int WM, bool STAT>
__global__ __launch_bounds__(256, 3) void k_gemm(
    const __bf16* A, const float* Ax, const float* ps, const float* pq,
    const float* lng, const float* lnb,
    const __bf16* __restrict__ Bt, const float* bias, const float* res,
    float* outf, __bf16* outb, float* ops, float* opq,
    int M, int N, int K, int ntx, int nty)
{
  __shared__ __align__(16) unsigned char smem[(MT + NT) * 256];
  gemm_tiles<MODE, RELU, BIAS, AMODE, MT, NT, WM, STAT, 1>(
      smem, A, Ax, ps, pq, lng, lnb, Bt, bias, res, outf, outb, ops, opq,
      M, N, K, ntx, nty);
}

// BK=128 wrapper (AMODE 0 only): (MT+NT)*512 B LDS; NT=32 -> 48 KB -> 3 blocks/CU
template <int MODE, bool RELU, bool BIAS, int MT, int NT, int WM, bool STAT>
__global__ __launch_bounds__(256, 3) void k_gemm2(
    const __bf16* A, const float* Ax, const float* ps, const float* pq,
    const float* lng, const float* lnb,
    const __bf16* __restrict__ Bt, const float* bias, const float* res,
    float* outf, __bf16* outb, float* ops, float* opq,
    int M, int N, int K, int ntx, int nty)
{
  __shared__ __align__(16) unsigned char smem[(MT + NT) * 512];
  gemm_tiles<MODE, RELU, BIAS, 0, MT, NT, WM, STAT, 2>(
      smem, A, Ax, ps, pq, lng, lnb, Bt, bias, res, outf, outb, ops, opq,
      M, N, K, ntx, nty);
}

// LM-head wrapper: 128x128 tile, BK=64, 64 KB LDS -> 2 blocks/CU
template <int MODE, bool RELU, bool BIAS, int AMODE, int MT, int NT, int WM, bool STAT>
__global__ __launch_bounds__(256, 2) void k_gemmL(
    const __bf16* A, const float* Ax, const float* ps, const float* pq,
    const float* lng, const float* lnb,
    const __bf16* __restrict__ Bt, const float* bias, const float* res,
    float* outf, __bf16* outb, float* ops, float* opq,
    int M, int N, int K, int ntx, int nty)
{
  __shared__ __align__(16) unsigned char smem[(MT + NT) * 256];
  gemm_tiles<MODE, RELU, BIAS, AMODE, MT, NT, WM, STAT, 1>(
      smem, A, Ax, ps, pq, lng, lnb, Bt, bias, res, outf, outb, ops, opq,
      M, N, K, ntx, nty);
}

// ---------------- fused masked attention: dbuf K/V LDS, reg prefetch, 1 barrier/tile ----------------
// Work-balanced block order: blockIdx 0..255 carry the longest q-tiles (one per CU),
// trailing 16 blocks are the 1-tile q_level=0 blocks that double up on CUs.
__global__ __launch_bounds__(256) void k_attnw(const __bf16* qkv, __bf16* ob)
{
  __shared__ __align__(16) __bf16 Ks[2][64][72];     // [buf][key row][hs]
  __shared__ __align__(16) __bf16 Vs[2][64][72];     // [buf][hs][key]
  __shared__ __align__(16) __bf16 Ps[4][16][72];     // per wave: q row x key (wave-private)

  const int tid = threadIdx.x;
  const int lane = tid & 63, w = tid >> 6;
  const int rm = lane & 15, g4 = lane >> 4;
  const int skey = tid >> 3;            // 0..31
  const int shs = (tid & 7) * 8;
  const size_t rsd = 1536;
  const f32x4 fz = {0.f, 0.f, 0.f, 0.f};

  // descending-work relabel: q_level 16..0 as blockIdx rises
  const int q_level = 16 - (blockIdx.x >> 4);
  const int bh = blockIdx.x & 15;
  const int b = bh >> 3, h = bh & 7;
  const int q0 = q_level * 64;
  const int qw = q0 + w * 16;

  const __bf16* qb = qkv + (size_t)b * TT1 * rsd + h * HSZ;
  const __bf16* kb = qb + 512;
  const __bf16* vb = qb + 1024;

  bf16x8 aq[2];
  {
    const __bf16* qp = qb + (size_t)(qw + rm) * rsd + 8 * g4;
    aq[0] = *(const bf16x8*)qp;
    aq[1] = *(const bf16x8*)(qp + 32);
  }

  int ae_[4];
#pragma unroll
  for (int r = 0; r < 4; r++) {
    int qr = qw + g4 * 4 + r;
    ae_[r] = (qr / 6 + 1) * 6;          // chunked-causal limit
  }

  float m_[4], l_[4];
  f32x4 accO[4];
#pragma unroll
  for (int j = 0; j < 4; j++) accO[j] = fz;
#pragma unroll
  for (int r = 0; r < 4; r++) { m_[r] = -1e30f; l_[r] = 0.f; }

  int aemax = ((q0 + 63) / 6 + 1) * 6;
  if (aemax > TT) aemax = TT;
  const int ntile = (aemax + 63) >> 6;  // 64-key main tiles cover [0, ntile*64) <= 1024

  // K/V register staging + buffered write helpers
  bf16x8 rk0, rk1, rv0, rv1;
  auto kvload = [&](int kt) {
    rk0 = *(const bf16x8*)(kb + (size_t)(kt + skey) * rsd + shs);
    rk1 = *(const bf16x8*)(kb + (size_t)(kt + skey + 32) * rsd + shs);
    rv0 = *(const bf16x8*)(vb + (size_t)(kt + skey) * rsd + shs);
    rv1 = *(const bf16x8*)(vb + (size_t)(kt + skey + 32) * rsd + shs);
  };
  auto kvwrite = [&](int buf) {
    *(bf16x8*)&Ks[buf][skey][shs]      = rk0;
    *(bf16x8*)&Ks[buf][skey + 32][shs] = rk1;
#pragma unroll
    for (int j = 0; j < 8; j++) {
      Vs[buf][shs + j][skey]      = rv0[j];
      Vs[buf][shs + j][skey + 32] = rv1[j];
    }
  };
  auto ktile = [&](int tt) { return (tt == ntile) ? TT : tt * 64; };

  // ---- prologue: tile 0 into buf 0 ----
  kvload(ktile(0));
  kvwrite(0);
  __syncthreads();

  int cur = 0;
  for (int tt = 0; tt <= ntile; ++tt) {
    const bool meta = (tt == ntile);
    const int kt = ktile(tt);
    const bool nxt = (tt < ntile);
    if (nxt) kvload(ktile(tt + 1));     // HBM latency hides under this tile's compute

    // S = Q K^T  (16 q x 64 keys per wave)
    f32x4 s[4];
    __builtin_amdgcn_s_setprio(1);
#pragma unroll
    for (int nt2 = 0; nt2 < 4; nt2++) {
      f32x4 a = fz;
      bf16x8 bk0 = *(const bf16x8*)&Ks[cur][nt2 * 16 + rm][8 * g4];
      bf16x8 bk1 = *(const bf16x8*)&Ks[cur][nt2 * 16 + rm][32 + 8 * g4];
      a = __builtin_amdgcn_mfma_f32_16x16x32_bf16(aq[0], bk0, a, 0, 0, 0);
      a = __builtin_amdgcn_mfma_f32_16x16x32_bf16(aq[1], bk1, a, 0, 0, 0);
      s[nt2] = a;
    }
    __builtin_amdgcn_s_setprio(0);

    float alpha[4];
#pragma unroll
    for (int r = 0; r < 4; r++) {
      int lim = meta ? TT1 : ae_[r];
      float sv[4];
#pragma unroll
      for (int i = 0; i < 4; i++) {
        sv[i] = s[i][r] * SCALE;
        if (kt + i * 16 + rm >= lim) sv[i] = -1e30f;
      }
      float tm = fmaxf(fmaxf(sv[0], sv[1]), fmaxf(sv[2], sv[3]));
#pragma unroll
      for (int msk = 1; msk < 16; msk <<= 1) tm = fmaxf(tm, __shfl_xor(tm, msk));
      float mn = fmaxf(m_[r], tm);
      float pp[4]; float ts = 0.f;
#pragma unroll
      for (int i = 0; i < 4; i++) { pp[i] = __expf(sv[i] - mn); ts += pp[i]; }
#pragma unroll
      for (int msk = 1; msk < 16; msk <<= 1) ts += __shfl_xor(ts, msk);
      alpha[r] = __expf(m_[r] - mn);
      l_[r] = l_[r] * alpha[r] + ts;
      m_[r] = mn;
#pragma unroll
      for (int i = 0; i < 4; i++) Ps[w][g4 * 4 + r][rm + i * 16] = f2bf(pp[i]);
    }
#pragma unroll
    for (int j = 0; j < 4; j++)
#pragma unroll
      for (int r = 0; r < 4; r++) accO[j][r] *= alpha[r];
    // Ps[w] is wave-private: intra-wave ds_write -> ds_read ordering is HW/compiler enforced

    bf16x8 pa0 = *(const bf16x8*)&Ps[w][rm][8 * g4];
    bf16x8 pa1 = *(const bf16x8*)&Ps[w][rm][32 + 8 * g4];
    __builtin_amdgcn_s_setprio(1);
#pragma unroll
    for (int j = 0; j < 4; j++) {
      bf16x8 bv0 = *(const bf16x8*)&Vs[cur][j * 16 + rm][8 * g4];
      bf16x8 bv1 = *(const bf16x8*)&Vs[cur][j * 16 + rm][32 + 8 * g4];
      accO[j] = __builtin_amdgcn_mfma_f32_16x16x32_bf16(pa0, bv0, accO[j], 0, 0, 0);
      accO[j] = __builtin_amdgcn_mfma_f32_16x16x32_bf16(pa1, bv1, accO[j], 0, 0, 0);
    }
    __builtin_amdgcn_s_setprio(0);

    if (nxt) {
      kvwrite(cur ^ 1);                 // other waves may still read buf[cur] - disjoint
      __syncthreads();                  // buf[cur^1] ready; prior reads of it long done
    }
    cur ^= 1;
  }

#pragma unroll
  for (int r = 0; r < 4; r++) {
    int q = qw + g4 * 4 + r;
    if (q < TT1) {
      float rl = 1.0f / l_[r];
#pragma unroll
      for (int j = 0; j < 4; j++)
        ob[((size_t)b * TT1 + q) * DD + h * HSZ + j * 16 + rm] = f2bf(accO[j][r] * rl);
    }
  }
}

// ---------------- host launcher ----------------
extern "C" void kernel_launch(void* const* d_in, const int* in_sizes, int n_in,
                              void* d_out, int out_size, void* d_ws, size_t ws_size,
                              hipStream_t stream)
{
  const int*   idx   = (const int*)d_in[0];
  const int*   midx  = (const int*)d_in[1];
  const float* tok   = (const float*)d_in[2];
  const float* metae = (const float*)d_in[3];
  const float* Wq    = (const float*)d_in[4];
  const float* Wk    = (const float*)d_in[5];
  const float* Wv    = (const float*)d_in[6];
  const float* Wo    = (const float*)d_in[7];
  const float* bo    = (const float*)d_in[8];
  const float* W1    = (const float*)d_in[9];
  const float* b1    = (const float*)d_in[10];
  const float* W2    = (const float*)d_in[11];
  const float* b2    = (const float*)d_in[12];
  const float* ln1g  = (const float*)d_in[13];
  const float* ln1b  = (const float*)d_in[14];
  const float* ln2g  = (const float*)d_in[15];
  const float* ln2b  = (const float*)d_in[16];
  const float* lnfg  = (const float*)d_in[17];
  const float* lnfb  = (const float*)d_in[18];
  const float* Wlm   = (const float*)d_in[19];
  const float* blm   = (const float*)d_in[20];
  float* out = (float*)d_out;

  char* p = (char*)d_ws;
  auto alloc = [&](size_t bytes) { void* r = (void*)p; p += (bytes + 255) & ~(size_t)255; return r; };
  float*  x     = (float*)alloc((size_t)MPAD * 512 * 4);
  float*  ps_   = (float*)alloc((size_t)MPAD * NPART * 4);
  float*  pq_   = (float*)alloc((size_t)MPAD * NPART * 4);
  __bf16* qkv   = (__bf16*)alloc((size_t)MPAD * 1536 * 2);
  __bf16* obuf  = (__bf16*)alloc((size_t)MPAD * 512 * 2);
  __bf16* f1    = (__bf16*)alloc((size_t)MPAD * 2048 * 2);
  __bf16* xf    = (__bf16*)alloc((size_t)2048 * 512 * 2);
  __bf16* wqkvb = (__bf16*)alloc((size_t)6 * 1536 * 512 * 2);
  __bf16* wob   = (__bf16*)alloc((size_t)6 * 512 * 512 * 2);
  __bf16* w1b   = (__bf16*)alloc((size_t)6 * 2048 * 512 * 2);
  __bf16* w2b   = (__bf16*)alloc((size_t)6 * 512 * 2048 * 2);
  __bf16* wlmb  = (__bf16*)alloc((size_t)NVOCAB * 512 * 2);
  (void)in_sizes; (void)n_in; (void)out_size; (void)ws_size;

  // 1) weight conversions (64x64 tiles) + embedding, one dispatch (8608 + 1030)
  k_tcvt8<<<dim3(9638), 256, 0, stream>>>(Wq, Wk, Wv, Wo, W1, W2, Wlm,
                                          wqkvb, wob, w1b, w2b, wlmb,
                                          idx, midx, tok, metae, x, ps_, pq_);

  for (int l = 0; l < LL; ++l) {
    // QKV projection with fused ln1 (64x64 tiles, BK=64, 816 blocks)
    k_gemm<0, false, false, 1, 64, 64, 4, false><<<dim3(816), 256, 0, stream>>>(
        nullptr, x, ps_, pq_, ln1g + l * 512, ln1b + l * 512,
        wqkvb + (size_t)l * 786432, nullptr, nullptr, nullptr, qkv,
        nullptr, nullptr, MROWS, 1536, 512, 34, 24);
    // attention (272 blocks, dbuf K/V, 1 barrier/tile, balanced order)
    k_attnw<<<dim3(272), 256, 0, stream>>>(qkv, obuf);
    // Wo projection + residual + LN partials (64x32 tiles, BK=128, 544 blocks)
    k_gemm2<1, false, true, 64, 32, 4, true><<<dim3(544), 256, 0, stream>>>(
        obuf, nullptr, nullptr, nullptr, nullptr, nullptr,
        wob + (size_t)l * 262144, bo + l * 512, x, x, nullptr,
        ps_, pq_, MROWS, 512, 512, 34, 16);
    // FFN1 with fused ln2 (64x64 tiles, BK=64, 1088 blocks)
    k_gemm<0, true, true, 1, 64, 64, 4, false><<<dim3(1088), 256, 0, stream>>>(
        nullptr, x, ps_, pq_, ln2g + l * 512, ln2b + l * 512,
        w1b + (size_t)l * 1048576, b1 + l * 2048, nullptr, nullptr, f1,
        nullptr, nullptr, MROWS, 2048, 512, 34, 32);
    // FFN2 + residual + LN partials (64x32 tiles, BK=128, 544 blocks)
    k_gemm2<1, false, true, 64, 32, 4, true><<<dim3(544), 256, 0, stream>>>(
        f1, nullptr, nullptr, nullptr, nullptr, nullptr,
        w2b + (size_t)l * 1048576, b2 + l * 512, x, x, nullptr,
        ps_, pq_, MROWS, 512, 2048, 34, 16);
  }

  // final LN -> compact bf16 rows, then LM head (128x128 tiles, 16x250 = 4000 blocks)
  k_lnpw<<<dim3(512), 256, 0, stream>>>(x, ps_, pq_, lnfg, lnfb, xf);
  k_gemmL<2, false, true, 0, 128, 128, 2, false><<<dim3(4000), 256, 0, stream>>>(
      xf, nullptr, nullptr, nullptr, nullptr, nullptr,
      wlmb, blm, nullptr, out, nullptr, nullptr, nullptr, 2048, NVOCAB, 512, 16, 250);
}